// Round 5
// baseline (8651.604 us; speedup 1.0000x reference)
//
#include <hip/hip_runtime.h>
#include <stdint.h>
#include <stddef.h>

// Problem constants (match reference)
#define BB 128
#define SS 128
#define EE 256
#define DD 512
#define KK 16
#define LL 1906   // 1 + 127*15
#define RR 2033   // 1 + 127*16
#define NSTEP 127

// workspace layout per row (floats): stride 2048
//  u[0]=flag_x_A u[32]=flag_x_B u[64]=flag_h_A u[96]=flag_h_B u[128]=flag_m
//  u[160]=marker payload, f[161]=new_t payload
//  f[256..511]=x_A, f[512..767]=x_B, f[768..1023]=h_A, f[1024..1279]=h_B
#define WS_ROW_STRIDE 2048

#define AT_ST(p, v)     __hip_atomic_store((p), (v), __ATOMIC_RELAXED, __HIP_MEMORY_SCOPE_AGENT)
#define AT_LD(p)        __hip_atomic_load((p), __ATOMIC_RELAXED, __HIP_MEMORY_SCOPE_AGENT)
#define AT_ST_REL(p, v) __hip_atomic_store((p), (v), __ATOMIC_RELEASE, __HIP_MEMORY_SCOPE_AGENT)
#define AT_LD_ACQ(p)    __hip_atomic_load((p), __ATOMIC_ACQUIRE, __HIP_MEMORY_SCOPE_AGENT)

static __device__ __forceinline__ void spin_ge(uint32_t* f, uint32_t want) {
  int guard = 0;
  while (AT_LD_ACQ(f) < want) {           // bounded: fail loudly, never hang
    __builtin_amdgcn_s_sleep(2);
    if (++guard > (1 << 22)) break;
  }
}

// ---------------- JAX threefry2x32 (bit-exact, partitionable) ----------------
static __device__ __forceinline__ uint32_t rotl32(uint32_t v, int r) {
  return (v << r) | (v >> (32 - r));
}

static __device__ __forceinline__ void tf2x32(uint32_t k0, uint32_t k1,
                                              uint32_t x0, uint32_t x1,
                                              uint32_t &o0, uint32_t &o1) {
  uint32_t ks2 = k0 ^ k1 ^ 0x1BD11BDAu;
  x0 += k0; x1 += k1;
#define TFR(r) { x0 += x1; x1 = rotl32(x1, (r)); x1 ^= x0; }
  TFR(13) TFR(15) TFR(26) TFR(6)
  x0 += k1;  x1 += ks2 + 1u;
  TFR(17) TFR(29) TFR(16) TFR(24)
  x0 += ks2; x1 += k0 + 2u;
  TFR(13) TFR(15) TFR(26) TFR(6)
  x0 += k0;  x1 += k1 + 3u;
  TFR(17) TFR(29) TFR(16) TFR(24)
  x0 += k1;  x1 += ks2 + 4u;
  TFR(13) TFR(15) TFR(26) TFR(6)
  x0 += ks2; x1 += k0 + 5u;
#undef TFR
  o0 = x0; o1 = x1;
}

static __device__ __forceinline__ float jax_gumbel(uint32_t bits) {
  float f = __uint_as_float((bits >> 9) | 0x3F800000u) - 1.0f;
  float u = fmaxf(f, 1.17549435e-38f);
  return -logf(-logf(u));
}

// 16-FMA macro: rows i..i+3 (w0..w3) x 4 columns (d0..d3)
#define FMA16(a4, w0, w1, w2, w3)                                              \
  d0 = fma((double)a4.x, (double)w0.x, d0); d1 = fma((double)a4.x, (double)w0.y, d1); \
  d2 = fma((double)a4.x, (double)w0.z, d2); d3 = fma((double)a4.x, (double)w0.w, d3); \
  d0 = fma((double)a4.y, (double)w1.x, d0); d1 = fma((double)a4.y, (double)w1.y, d1); \
  d2 = fma((double)a4.y, (double)w1.z, d2); d3 = fma((double)a4.y, (double)w1.w, d3); \
  d0 = fma((double)a4.z, (double)w2.x, d0); d1 = fma((double)a4.z, (double)w2.y, d1); \
  d2 = fma((double)a4.z, (double)w2.z, d2); d3 = fma((double)a4.z, (double)w2.w, d3); \
  d0 = fma((double)a4.w, (double)w3.x, d0); d1 = fma((double)a4.w, (double)w3.y, d1); \
  d2 = fma((double)a4.w, (double)w3.z, d2); d3 = fma((double)a4.w, (double)w3.w, d3);

__global__ void init_flags_kernel(uint32_t* ws) {
  // grid 128 x block 64; zero the 5 flags of each row
  if (threadIdx.x < 5) ws[(size_t)blockIdx.x * WS_ROW_STRIDE + threadIdx.x * 32] = 0u;
}

// ---------------- pair kernel: 2 CUs per row, column-split weights ----------------
__global__ __launch_bounds__(1024, 4) void rnn_pair_kernel(
    const int*   __restrict__ marker_data,
    const float* __restrict__ time_data,
    const float* __restrict__ mask_data,
    const float* __restrict__ embedding,     // (50000,E)
    const int*   __restrict__ neighbor_list, // (50000,K)
    const float* __restrict__ neighbor_prob, // (50000,K)
    const float* __restrict__ W_te, const float* __restrict__ b_te,
    const float* __restrict__ W_el, const float* __restrict__ b_el,
    const float* __restrict__ W_ih, const float* __restrict__ b_ih,
    const float* __restrict__ W_hh, const float* __restrict__ b_hh,
    const float* __restrict__ W_time, const float* __restrict__ b_time,
    const float* __restrict__ W_mk, const float* __restrict__ b_mk,
    float* __restrict__ ws,
    float* __restrict__ out)
{
  __shared__ double s_pd[16][256];    // streaming partials (W_el, then W_ih)  32 KB
  __shared__ double s_pd2[16][256];   // W_hh partials (persist P0->P3)        32 KB
  __shared__ float  s_prob[LL];
  __shared__ int    s_cand[LL];
  __shared__ float  s_nrec[RR];
  __shared__ float  s_x[DD];
  __shared__ float  s_h[DD];
  __shared__ float  s_vec[EE];
  __shared__ double s_edot[KK];
  __shared__ double s_rt[8];
  __shared__ double s_rm[8];
  __shared__ float  s_red_z[16];
  __shared__ int    s_red_i[16];
  __shared__ int    s_neigh[KK];
  __shared__ float  s_last_t;
  __shared__ int    s_last_m;
  __shared__ int    s_chosen;
  __shared__ float  s_newt;
  __shared__ uint32_t s_k0, s_k1;

  const int  bid  = blockIdx.x;
  const bool isA  = (bid < BB);
  const int  row  = isA ? bid : bid - BB;
  const int  tid  = threadIdx.x;
  const int  own0 = isA ? 0 : 256;        // own output-column base
  const int  oq   = own0 >> 2;            // own base in float4 units

  float*    wrow   = ws + (size_t)row * WS_ROW_STRIDE;
  uint32_t* urow   = (uint32_t*)wrow;
  uint32_t* fx_own = urow + (isA ? 0 : 32);
  uint32_t* fx_oth = urow + (isA ? 32 : 0);
  uint32_t* fh_own = urow + (isA ? 64 : 96);
  uint32_t* fh_oth = urow + (isA ? 96 : 64);
  uint32_t* fm     = urow + 128;
  uint32_t* pay_m  = urow + 160;
  float*    pay_t  = wrow + 161;
  float*    x_own  = wrow + (isA ? 256 : 512);
  float*    x_oth  = wrow + (isA ? 512 : 256);
  float*    h_own  = wrow + (isA ? 768 : 1024);
  float*    h_oth  = wrow + (isA ? 1024 : 768);

  // ---- init
  if (isA) {
    for (int i = tid; i < LL; i += 1024) { s_prob[i] = 0.0f; s_cand[i] = 0; }
    for (int i = tid; i < RR; i += 1024) s_nrec[i] = 1.0f;
  }
  if (tid < DD) s_h[tid] = 0.0f;
  if (tid == 0) {
    int   m0 = marker_data[row * SS];
    float t0 = time_data[row * SS];
    s_last_m = m0; s_last_t = t0; s_chosen = 0;
    if (isA) {
      s_cand[0] = m0; s_prob[0] = 1.0f;
      out[0 * BB * SS + row * SS + 0] = (float)m0;
      out[1 * BB * SS + row * SS + 0] = t0;
      out[2 * BB * SS + row * SS + 0] = mask_data[row * SS];
      out[3 * BB * SS + row * SS + 0] = 1.0f;
      out[4 * BB * SS + row * SS + 0] = 1.0f;
    }
  }
  __syncthreads();

  const int jg = tid & 63;    // 4 own columns: own0+4*jg .. +3
  const int sl = tid >> 6;    // 16 K-slices

  for (int t = 0; t < NSTEP; ++t) {
    // ---- P0: h_t @ W_hh[:, own half] -> s_pd2 (x-independent; B runs this
    //      while A finishes the previous step's sampling)
    {
      const int i0 = sl << 5;   // 32 rows per slice
      const float4* W4 = (const float4*)W_hh + (size_t)i0 * 128 + oq + jg;
      double d0 = 0.0, d1 = 0.0, d2 = 0.0, d3 = 0.0;
#pragma unroll 4
      for (int i = 0; i < 32; i += 4) {
        float4 a4 = *(const float4*)&s_h[i0 + i];
        float4 w0 = W4[0], w1 = W4[128], w2 = W4[256], w3 = W4[384];
        W4 += 512;
        FMA16(a4, w0, w1, w2, w3)
      }
      double* pd = &s_pd2[sl][4 * jg];
      pd[0] = d0; pd[1] = d1; pd[2] = d2; pd[3] = d3;
    }

    // ---- P1: B acquires marker/new_t broadcast (t>=1); A already has them
    if (!isA && t > 0 && tid == 0) {
      spin_ge(fm, (uint32_t)t);
      s_last_m = (int)AT_LD(pay_m);
      s_last_t = AT_LD(pay_t);
    }
    __syncthreads();  // (a) pd2 + s_last_m/t visible
    const int   m  = s_last_m;
    const float lt = s_last_t;

    if (tid < EE) {
      float te = __fadd_rn(__fmul_rn(lt, W_te[tid]), b_te[tid]);
      s_vec[tid] = __fadd_rn(embedding[(size_t)m * EE + tid], __fmul_rn(0.1f, te));
    }
    if (isA) {
      if (tid == 768) {
        uint32_t o0, o1;
        tf2x32(0u, 42u, 0u, (uint32_t)t, o0, o1);
        s_k0 = o0; s_k1 = o1;
      }
      if (tid >= 256 && tid < 256 + KK) {
        int k = tid - 256;
        int nb = neighbor_list[(size_t)m * KK + k];
        s_neigh[k] = nb;
        s_nrec[1 + t * KK + k] = neighbor_prob[(size_t)m * KK + k];
        if (k >= 1) s_cand[1 + t * (KK - 1) + (k - 1)] = nb;
      }
    }
    __syncthreads();  // (b) vec (+neigh) ready

    // ---- P2: vec @ W_el[:, own half] -> s_pd ; A prefetches neighbor emb rows
    float4 ev0 = make_float4(0.f, 0.f, 0.f, 0.f), ev1 = ev0;
    if (isA && tid >= 512) {
      int k = (tid - 512) >> 5, l32 = tid & 31;
      const float4* er = (const float4*)(embedding + (size_t)s_neigh[k] * EE);
      ev0 = er[2 * l32]; ev1 = er[2 * l32 + 1];
    }
    {
      const int i0 = sl << 4;   // 16 rows per slice (K=256)
      const float4* W4 = (const float4*)W_el + (size_t)i0 * 128 + oq + jg;
      double d0 = 0.0, d1 = 0.0, d2 = 0.0, d3 = 0.0;
#pragma unroll 4
      for (int i = 0; i < 16; i += 4) {
        float4 a4 = *(const float4*)&s_vec[i0 + i];
        float4 w0 = W4[0], w1 = W4[128], w2 = W4[256], w3 = W4[384];
        W4 += 512;
        FMA16(a4, w0, w1, w2, w3)
      }
      double* pd = &s_pd[sl][4 * jg];
      pd[0] = d0; pd[1] = d1; pd[2] = d2; pd[3] = d3;
    }
    __syncthreads();  // (c)

    // ---- x own-half combine + exchange
    if (tid < 256) {
      double d = (((s_pd[0][tid] + s_pd[1][tid]) + (s_pd[2][tid] + s_pd[3][tid]))
                + ((s_pd[4][tid] + s_pd[5][tid]) + (s_pd[6][tid] + s_pd[7][tid])))
               + (((s_pd[8][tid] + s_pd[9][tid]) + (s_pd[10][tid] + s_pd[11][tid]))
                + ((s_pd[12][tid] + s_pd[13][tid]) + (s_pd[14][tid] + s_pd[15][tid])));
      float z = __fadd_rn((float)d, b_el[own0 + tid]);
      float xv = (z >= 0.0f) ? z : __fmul_rn(0.01f, z);
      s_x[own0 + tid] = xv;
      AT_ST(&x_own[tid], xv);
    }
    __syncthreads();  // (d) — barrier drain pushes x_own stores to coherence point
    if (tid == 0) {
      AT_ST_REL(fx_own, (uint32_t)(t + 1));
      spin_ge(fx_oth, (uint32_t)(t + 1));
    }
    __syncthreads();  // (e)
    if (tid < 256) s_x[(own0 ^ 256) + tid] = AT_LD(&x_oth[tid]);
    __syncthreads();  // (f) full x ready

    // ---- P3: x @ W_ih[:, own half] -> s_pd
    {
      const int i0 = sl << 5;   // 32 rows per slice (K=512)
      const float4* W4 = (const float4*)W_ih + (size_t)i0 * 128 + oq + jg;
      double d0 = 0.0, d1 = 0.0, d2 = 0.0, d3 = 0.0;
#pragma unroll 4
      for (int i = 0; i < 32; i += 4) {
        float4 a4 = *(const float4*)&s_x[i0 + i];
        float4 w0 = W4[0], w1 = W4[128], w2 = W4[256], w3 = W4[384];
        W4 += 512;
        FMA16(a4, w0, w1, w2, w3)
      }
      double* pd = &s_pd[sl][4 * jg];
      pd[0] = d0; pd[1] = d1; pd[2] = d2; pd[3] = d3;
    }
    __syncthreads();  // (g)

    // ---- h own-half combine (tanh) + exchange
    if (tid < 256) {
      int j = own0 + tid;
      double ih = (((s_pd[0][tid] + s_pd[1][tid]) + (s_pd[2][tid] + s_pd[3][tid]))
                 + ((s_pd[4][tid] + s_pd[5][tid]) + (s_pd[6][tid] + s_pd[7][tid])))
                + (((s_pd[8][tid] + s_pd[9][tid]) + (s_pd[10][tid] + s_pd[11][tid]))
                 + ((s_pd[12][tid] + s_pd[13][tid]) + (s_pd[14][tid] + s_pd[15][tid])));
      double hh = (((s_pd2[0][tid] + s_pd2[1][tid]) + (s_pd2[2][tid] + s_pd2[3][tid]))
                 + ((s_pd2[4][tid] + s_pd2[5][tid]) + (s_pd2[6][tid] + s_pd2[7][tid])))
                + (((s_pd2[8][tid] + s_pd2[9][tid]) + (s_pd2[10][tid] + s_pd2[11][tid]))
                 + ((s_pd2[12][tid] + s_pd2[13][tid]) + (s_pd2[14][tid] + s_pd2[15][tid])));
      float p = __fadd_rn(__fadd_rn(__fadd_rn((float)ih, b_ih[j]), (float)hh), b_hh[j]);
      float hf = (float)tanh((double)p);
      s_h[j] = hf;
      AT_ST(&h_own[tid], hf);
    }
    __syncthreads();  // (h)
    if (tid == 0) {
      AT_ST_REL(fh_own, (uint32_t)(t + 1));
      spin_ge(fh_oth, (uint32_t)(t + 1));
    }
    __syncthreads();  // (i)
    if (tid < 256) s_h[(own0 ^ 256) + tid] = AT_LD(&h_oth[tid]);
    __syncthreads();  // (j) full h_{t+1} ready — B proceeds to next iter's P0

    // ---- P4 (A only): time/score/softmax/sample/output/broadcast
    if (isA) {
      if (tid < DD) {
        double hv = (double)s_h[tid];
        double pt = hv * (double)W_time[tid];
        double pm = hv * (double)W_mk[EE + tid];
        for (int off = 32; off > 0; off >>= 1) {
          pt += __shfl_down(pt, off);
          pm += __shfl_down(pm, off);
        }
        if ((tid & 63) == 0) { s_rt[tid >> 6] = pt; s_rm[tid >> 6] = pm; }
      } else {
        int l32 = tid & 31;
        const float4* wm4 = (const float4*)W_mk;
        float4 wm0 = wm4[2 * l32], wm1 = wm4[2 * l32 + 1];
        double acc = 0.0;
        acc = fma((double)ev0.x, (double)wm0.x, acc);
        acc = fma((double)ev0.y, (double)wm0.y, acc);
        acc = fma((double)ev0.z, (double)wm0.z, acc);
        acc = fma((double)ev0.w, (double)wm0.w, acc);
        acc = fma((double)ev1.x, (double)wm1.x, acc);
        acc = fma((double)ev1.y, (double)wm1.y, acc);
        acc = fma((double)ev1.z, (double)wm1.z, acc);
        acc = fma((double)ev1.w, (double)wm1.w, acc);
        for (int off = 16; off > 0; off >>= 1) acc += __shfl_down(acc, off, 32);
        if (l32 == 0) s_edot[(tid - 512) >> 5] = acc;
      }
      __syncthreads();  // (k)

      if (tid < KK) {
        double hmk = ((s_rm[0] + s_rm[1]) + (s_rm[2] + s_rm[3]))
                   + ((s_rm[4] + s_rm[5]) + (s_rm[6] + s_rm[7]));
        float sc = __fadd_rn((float)(s_edot[tid] + hmk), b_mk[0]);
        float mx = sc;
        for (int k = 0; k < KK; ++k) mx = fmaxf(mx, __shfl(sc, k));
        float ee = expf(__fsub_rn(sc, mx));
        float ssum = 0.0f;
        for (int k = 0; k < KK; ++k) ssum = __fadd_rn(ssum, __shfl(ee, k));
        float cp = s_prob[s_chosen];
        float at = __fmul_rn(cp, __fdiv_rn(ee, ssum));
        if (tid == 0) s_prob[s_chosen] = at;
        else          s_prob[1 + t * (KK - 1) + (tid - 1)] = at;
      } else if (tid == 16) {
        double ht = ((s_rt[0] + s_rt[1]) + (s_rt[2] + s_rt[3]))
                  + ((s_rt[4] + s_rt[5]) + (s_rt[6] + s_rt[7]));
        float td = __fadd_rn((float)ht, b_time[0]);
        float sp = __fadd_rn(fmaxf(td, 0.0f), log1pf(expf(-fabsf(td))));
        s_newt = __fadd_rn(s_last_t, sp);
      }
      __syncthreads();  // (l)

      const int active = 16 + 15 * t;
      const uint32_t kk0 = s_k0, kk1 = s_k1;
      float bz = -3.0e38f;
      int   bi = 0x7FFFFFFF;
      for (int l = tid; l < active; l += 1024) {
        uint32_t i = (uint32_t)(row * LL + l);
        uint32_t o0, o1;
        tf2x32(kk0, kk1, 0u, i, o0, o1);
        float g  = jax_gumbel(o0 ^ o1);
        float pr = s_prob[l];
        float z  = (pr > 0.0f) ? __fadd_rn(logf(fmaxf(pr, 1e-38f)), g)
                               : __fadd_rn(-1e30f, g);
        if (z > bz) { bz = z; bi = l; }
      }
      for (int off = 32; off > 0; off >>= 1) {
        float oz = __shfl_down(bz, off);
        int   oi = __shfl_down(bi, off);
        if (oz > bz || (oz == bz && oi < bi)) { bz = oz; bi = oi; }
      }
      if ((tid & 63) == 0) { s_red_z[tid >> 6] = bz; s_red_i[tid >> 6] = bi; }
      __syncthreads();  // (m)

      if (tid == 0) {
        float z0 = s_red_z[0]; int i0 = s_red_i[0];
        for (int w = 1; w < 16; ++w) {
          if (s_red_z[w] > z0 || (s_red_z[w] == z0 && s_red_i[w] < i0)) {
            z0 = s_red_z[w]; i0 = s_red_i[w];
          }
        }
        int   nm  = s_cand[i0];
        float np_ = s_nrec[i0];
        float sp_ = s_prob[i0];
        float nt  = s_newt;
        out[0 * BB * SS + row * SS + (t + 1)] = (float)nm;
        out[1 * BB * SS + row * SS + (t + 1)] = nt;
        out[2 * BB * SS + row * SS + (t + 1)] = (nt < 1000.0f) ? 1.0f : 0.0f;
        out[3 * BB * SS + row * SS + (t + 1)] = np_;
        out[4 * BB * SS + row * SS + (t + 1)] = sp_;
        s_chosen = i0; s_last_m = nm; s_last_t = nt;
        // broadcast to B (thread-0's own stores; release orders them)
        AT_ST(pay_m, (uint32_t)nm);
        AT_ST(pay_t, nt);
        AT_ST_REL(fm, (uint32_t)(t + 1));
      }
      __syncthreads();  // (n)
    }
  }
}

extern "C" void kernel_launch(void* const* d_in, const int* in_sizes, int n_in,
                              void* d_out, int out_size, void* d_ws, size_t ws_size,
                              hipStream_t stream) {
  (void)in_sizes; (void)n_in; (void)out_size;
  if (ws_size < (size_t)BB * WS_ROW_STRIDE * 4) return;  // fail loudly if ws too small
  const int*   marker_data   = (const int*)  d_in[0];
  const float* time_data     = (const float*)d_in[1];
  const float* mask_data     = (const float*)d_in[2];
  const float* embedding     = (const float*)d_in[3];
  const int*   neighbor_list = (const int*)  d_in[4];
  const float* neighbor_prob = (const float*)d_in[5];
  const float* W_te   = (const float*)d_in[6];
  const float* b_te   = (const float*)d_in[7];
  const float* W_el   = (const float*)d_in[8];
  const float* b_el   = (const float*)d_in[9];
  const float* W_ih   = (const float*)d_in[10];
  const float* b_ih   = (const float*)d_in[11];
  const float* W_hh   = (const float*)d_in[12];
  const float* b_hh   = (const float*)d_in[13];
  const float* W_time = (const float*)d_in[14];
  const float* b_time = (const float*)d_in[15];
  const float* W_mk   = (const float*)d_in[16];
  const float* b_mk   = (const float*)d_in[17];
  float* out = (float*)d_out;
  float* ws  = (float*)d_ws;

  hipLaunchKernelGGL(init_flags_kernel, dim3(BB), dim3(64), 0, stream, (uint32_t*)d_ws);
  hipLaunchKernelGGL(rnn_pair_kernel, dim3(2 * BB), dim3(1024), 0, stream,
                     marker_data, time_data, mask_data, embedding,
                     neighbor_list, neighbor_prob,
                     W_te, b_te, W_el, b_el, W_ih, b_ih, W_hh, b_hh,
                     W_time, b_time, W_mk, b_mk, ws, out);
}

// Round 6
// 5336.694 us; speedup vs baseline: 1.6212x; 1.6212x over previous
//
#include <hip/hip_runtime.h>
#include <stdint.h>
#include <stddef.h>

// Problem constants (match reference)
#define BB 128
#define SS 128
#define EE 256
#define DD 512
#define KK 16
#define LL 1906   // 1 + 127*15
#define RR 2033   // 1 + 127*16
#define NSTEP 127

// ---- cross-block comm: tagged 64-bit words, relaxed agent atomics ONLY.
// (acquire/release at agent scope emit L2 invalidates/writebacks on gfx950's
//  non-coherent per-XCD L2s — R5 showed that poisons the L2 weight stream.
//  Relaxed atomic load/store bypass caches for that address only; tag+value
//  packed in one word gives consistency without any fence.)
// Layout per row (u64): [0..255]=x_A [256..511]=x_B [512..767]=h_A
// [768..1023]=h_B [1024]=marker [1025]=new_t ; stride 1040.
#define ROW_U64 1040
__device__ uint64_t g_comm[(size_t)BB * ROW_U64];

static __device__ __forceinline__ void st_pack(uint64_t* p, uint32_t tag, uint32_t val) {
  __hip_atomic_store(p, ((uint64_t)tag << 32) | (uint64_t)val,
                     __ATOMIC_RELAXED, __HIP_MEMORY_SCOPE_AGENT);
}
static __device__ __forceinline__ uint32_t poll_pack(uint64_t* p, uint32_t tag) {
  int guard = 0;
  for (;;) {
    uint64_t w = __hip_atomic_load(p, __ATOMIC_RELAXED, __HIP_MEMORY_SCOPE_AGENT);
    if ((uint32_t)(w >> 32) == tag) return (uint32_t)w;
    __builtin_amdgcn_s_sleep(1);
    if (++guard > (1 << 21)) return (uint32_t)w;   // fail loudly, never hang
  }
}

__global__ void init_comm_kernel() {
  size_t i = (size_t)blockIdx.x * 1024 + threadIdx.x;
  if (i < (size_t)BB * ROW_U64) g_comm[i] = 0ull;
}

// ---------------- JAX threefry2x32 (bit-exact, partitionable) ----------------
static __device__ __forceinline__ uint32_t rotl32(uint32_t v, int r) {
  return (v << r) | (v >> (32 - r));
}

static __device__ __forceinline__ void tf2x32(uint32_t k0, uint32_t k1,
                                              uint32_t x0, uint32_t x1,
                                              uint32_t &o0, uint32_t &o1) {
  uint32_t ks2 = k0 ^ k1 ^ 0x1BD11BDAu;
  x0 += k0; x1 += k1;
#define TFR(r) { x0 += x1; x1 = rotl32(x1, (r)); x1 ^= x0; }
  TFR(13) TFR(15) TFR(26) TFR(6)
  x0 += k1;  x1 += ks2 + 1u;
  TFR(17) TFR(29) TFR(16) TFR(24)
  x0 += ks2; x1 += k0 + 2u;
  TFR(13) TFR(15) TFR(26) TFR(6)
  x0 += k0;  x1 += k1 + 3u;
  TFR(17) TFR(29) TFR(16) TFR(24)
  x0 += k1;  x1 += ks2 + 4u;
  TFR(13) TFR(15) TFR(26) TFR(6)
  x0 += ks2; x1 += k0 + 5u;
#undef TFR
  o0 = x0; o1 = x1;
}

static __device__ __forceinline__ float jax_gumbel(uint32_t bits) {
  float f = __uint_as_float((bits >> 9) | 0x3F800000u) - 1.0f;
  float u = fmaxf(f, 1.17549435e-38f);
  return -logf(-logf(u));
}

// 16-FMA macro: rows i..i+3 (w0..w3) x 4 columns (d0..d3)
#define FMA16(a4, w0, w1, w2, w3)                                              \
  d0 = fma((double)a4.x, (double)w0.x, d0); d1 = fma((double)a4.x, (double)w0.y, d1); \
  d2 = fma((double)a4.x, (double)w0.z, d2); d3 = fma((double)a4.x, (double)w0.w, d3); \
  d0 = fma((double)a4.y, (double)w1.x, d0); d1 = fma((double)a4.y, (double)w1.y, d1); \
  d2 = fma((double)a4.y, (double)w1.z, d2); d3 = fma((double)a4.y, (double)w1.w, d3); \
  d0 = fma((double)a4.z, (double)w2.x, d0); d1 = fma((double)a4.z, (double)w2.y, d1); \
  d2 = fma((double)a4.z, (double)w2.z, d2); d3 = fma((double)a4.z, (double)w2.w, d3); \
  d0 = fma((double)a4.w, (double)w3.x, d0); d1 = fma((double)a4.w, (double)w3.y, d1); \
  d2 = fma((double)a4.w, (double)w3.z, d2); d3 = fma((double)a4.w, (double)w3.w, d3);

// ---------------- pair kernel: 2 CUs per row, column-split weights ----------------
__global__ __launch_bounds__(1024, 4) void rnn_pair_kernel(
    const int*   __restrict__ marker_data,
    const float* __restrict__ time_data,
    const float* __restrict__ mask_data,
    const float* __restrict__ embedding,     // (50000,E)
    const int*   __restrict__ neighbor_list, // (50000,K)
    const float* __restrict__ neighbor_prob, // (50000,K)
    const float* __restrict__ W_te, const float* __restrict__ b_te,
    const float* __restrict__ W_el, const float* __restrict__ b_el,
    const float* __restrict__ W_ih, const float* __restrict__ b_ih,
    const float* __restrict__ W_hh, const float* __restrict__ b_hh,
    const float* __restrict__ W_time, const float* __restrict__ b_time,
    const float* __restrict__ W_mk, const float* __restrict__ b_mk,
    float* __restrict__ out)
{
  __shared__ double s_pd[16][256];    // streaming partials (W_el, then W_ih)  32 KB
  __shared__ double s_pd2[16][256];   // W_hh partials (persist P0->combine)   32 KB
  __shared__ float  s_prob[LL];
  __shared__ int    s_cand[LL];
  __shared__ float  s_nrec[RR];
  __shared__ float  s_x[DD];
  __shared__ float  s_h[DD];
  __shared__ float  s_vec[EE];
  __shared__ double s_edot[KK];
  __shared__ double s_rt[8];
  __shared__ double s_rm[8];
  __shared__ float  s_red_z[16];
  __shared__ int    s_red_i[16];
  __shared__ int    s_neigh[KK];
  __shared__ float  s_last_t;
  __shared__ int    s_last_m;
  __shared__ int    s_chosen;
  __shared__ float  s_newt;
  __shared__ uint32_t s_k0, s_k1;

  const int  bid  = blockIdx.x;
  const bool isA  = (bid < BB);
  const int  row  = isA ? bid : bid - BB;
  const int  tid  = threadIdx.x;
  const int  own0 = isA ? 0 : 256;        // own output-column base
  const int  oq   = own0 >> 2;            // own base in float4 units

  uint64_t* crow   = g_comm + (size_t)row * ROW_U64;
  uint64_t* x_own  = crow + (isA ? 0 : 256);
  uint64_t* x_oth  = crow + (isA ? 256 : 0);
  uint64_t* h_own  = crow + (isA ? 512 : 768);
  uint64_t* h_oth  = crow + (isA ? 768 : 512);
  uint64_t* w_mark = crow + 1024;
  uint64_t* w_time = crow + 1025;

  // ---- init
  if (isA) {
    for (int i = tid; i < LL; i += 1024) { s_prob[i] = 0.0f; s_cand[i] = 0; }
    for (int i = tid; i < RR; i += 1024) s_nrec[i] = 1.0f;
  }
  if (tid < DD) s_h[tid] = 0.0f;
  if (tid == 0) {
    int   m0 = marker_data[row * SS];
    float t0 = time_data[row * SS];
    s_last_m = m0; s_last_t = t0; s_chosen = 0;
    if (isA) {
      s_cand[0] = m0; s_prob[0] = 1.0f;
      out[0 * BB * SS + row * SS + 0] = (float)m0;
      out[1 * BB * SS + row * SS + 0] = t0;
      out[2 * BB * SS + row * SS + 0] = mask_data[row * SS];
      out[3 * BB * SS + row * SS + 0] = 1.0f;
      out[4 * BB * SS + row * SS + 0] = 1.0f;
    }
  }
  __syncthreads();

  const int jg = tid & 63;    // 4 own columns: own0+4*jg .. +3
  const int sl = tid >> 6;    // 16 K-slices

  for (int t = 0; t < NSTEP; ++t) {
    // ---- P0: h_t @ W_hh[:, own half] -> s_pd2 (x-independent; B runs this
    //      while A finishes the previous step's sampling)
    {
      const int i0 = sl << 5;   // 32 rows per slice
      const float4* W4 = (const float4*)W_hh + (size_t)i0 * 128 + oq + jg;
      double d0 = 0.0, d1 = 0.0, d2 = 0.0, d3 = 0.0;
#pragma unroll 4
      for (int i = 0; i < 32; i += 4) {
        float4 a4 = *(const float4*)&s_h[i0 + i];
        float4 w0 = W4[0], w1 = W4[128], w2 = W4[256], w3 = W4[384];
        W4 += 512;
        FMA16(a4, w0, w1, w2, w3)
      }
      double* pd = &s_pd2[sl][4 * jg];
      pd[0] = d0; pd[1] = d1; pd[2] = d2; pd[3] = d3;
    }

    // ---- P1: B acquires marker/new_t broadcast (t>=1); tagged words, relaxed
    if (!isA && t > 0 && tid == 0) {
      uint32_t mv = poll_pack(w_mark, (uint32_t)t);
      uint32_t tv = poll_pack(w_time, (uint32_t)t);
      s_last_m = (int)mv;
      s_last_t = __uint_as_float(tv);
    }
    __syncthreads();  // (a) pd2 + s_last_m/t visible
    const int   m  = s_last_m;
    const float lt = s_last_t;

    if (tid < EE) {
      float te = __fadd_rn(__fmul_rn(lt, W_te[tid]), b_te[tid]);
      s_vec[tid] = __fadd_rn(embedding[(size_t)m * EE + tid], __fmul_rn(0.1f, te));
    }
    if (isA) {
      if (tid == 768) {
        uint32_t o0, o1;
        tf2x32(0u, 42u, 0u, (uint32_t)t, o0, o1);
        s_k0 = o0; s_k1 = o1;
      }
      if (tid >= 256 && tid < 256 + KK) {
        int k = tid - 256;
        int nb = neighbor_list[(size_t)m * KK + k];
        s_neigh[k] = nb;
        s_nrec[1 + t * KK + k] = neighbor_prob[(size_t)m * KK + k];
        if (k >= 1) s_cand[1 + t * (KK - 1) + (k - 1)] = nb;
      }
    }
    __syncthreads();  // (b) vec (+neigh) ready

    // ---- P2: vec @ W_el[:, own half] -> s_pd ; A prefetches neighbor emb rows
    float4 ev0 = make_float4(0.f, 0.f, 0.f, 0.f), ev1 = ev0;
    if (isA && tid >= 512) {
      int k = (tid - 512) >> 5, l32 = tid & 31;
      const float4* er = (const float4*)(embedding + (size_t)s_neigh[k] * EE);
      ev0 = er[2 * l32]; ev1 = er[2 * l32 + 1];
    }
    {
      const int i0 = sl << 4;   // 16 rows per slice (K=256)
      const float4* W4 = (const float4*)W_el + (size_t)i0 * 128 + oq + jg;
      double d0 = 0.0, d1 = 0.0, d2 = 0.0, d3 = 0.0;
#pragma unroll 4
      for (int i = 0; i < 16; i += 4) {
        float4 a4 = *(const float4*)&s_vec[i0 + i];
        float4 w0 = W4[0], w1 = W4[128], w2 = W4[256], w3 = W4[384];
        W4 += 512;
        FMA16(a4, w0, w1, w2, w3)
      }
      double* pd = &s_pd[sl][4 * jg];
      pd[0] = d0; pd[1] = d1; pd[2] = d2; pd[3] = d3;
    }
    __syncthreads();  // (c)

    // ---- x own-half combine + tagged exchange (store own, poll other)
    if (tid < 256) {
      double d = (((s_pd[0][tid] + s_pd[1][tid]) + (s_pd[2][tid] + s_pd[3][tid]))
                + ((s_pd[4][tid] + s_pd[5][tid]) + (s_pd[6][tid] + s_pd[7][tid])))
               + (((s_pd[8][tid] + s_pd[9][tid]) + (s_pd[10][tid] + s_pd[11][tid]))
                + ((s_pd[12][tid] + s_pd[13][tid]) + (s_pd[14][tid] + s_pd[15][tid])));
      float z = __fadd_rn((float)d, b_el[own0 + tid]);
      float xv = (z >= 0.0f) ? z : __fmul_rn(0.01f, z);
      s_x[own0 + tid] = xv;
      st_pack(&x_own[tid], (uint32_t)(t + 1), __float_as_uint(xv));
      __atomic_signal_fence(__ATOMIC_SEQ_CST);   // compiler-only: store before poll
      uint32_t xb = poll_pack(&x_oth[tid], (uint32_t)(t + 1));
      s_x[(own0 ^ 256) + tid] = __uint_as_float(xb);
    }
    __syncthreads();  // (f) full x ready

    // ---- P3: x @ W_ih[:, own half] -> s_pd
    {
      const int i0 = sl << 5;   // 32 rows per slice (K=512)
      const float4* W4 = (const float4*)W_ih + (size_t)i0 * 128 + oq + jg;
      double d0 = 0.0, d1 = 0.0, d2 = 0.0, d3 = 0.0;
#pragma unroll 4
      for (int i = 0; i < 32; i += 4) {
        float4 a4 = *(const float4*)&s_x[i0 + i];
        float4 w0 = W4[0], w1 = W4[128], w2 = W4[256], w3 = W4[384];
        W4 += 512;
        FMA16(a4, w0, w1, w2, w3)
      }
      double* pd = &s_pd[sl][4 * jg];
      pd[0] = d0; pd[1] = d1; pd[2] = d2; pd[3] = d3;
    }
    __syncthreads();  // (g)

    // ---- h own-half combine (tanh) + tagged exchange
    if (tid < 256) {
      int j = own0 + tid;
      double ih = (((s_pd[0][tid] + s_pd[1][tid]) + (s_pd[2][tid] + s_pd[3][tid]))
                 + ((s_pd[4][tid] + s_pd[5][tid]) + (s_pd[6][tid] + s_pd[7][tid])))
                + (((s_pd[8][tid] + s_pd[9][tid]) + (s_pd[10][tid] + s_pd[11][tid]))
                 + ((s_pd[12][tid] + s_pd[13][tid]) + (s_pd[14][tid] + s_pd[15][tid])));
      double hh = (((s_pd2[0][tid] + s_pd2[1][tid]) + (s_pd2[2][tid] + s_pd2[3][tid]))
                 + ((s_pd2[4][tid] + s_pd2[5][tid]) + (s_pd2[6][tid] + s_pd2[7][tid])))
                + (((s_pd2[8][tid] + s_pd2[9][tid]) + (s_pd2[10][tid] + s_pd2[11][tid]))
                 + ((s_pd2[12][tid] + s_pd2[13][tid]) + (s_pd2[14][tid] + s_pd2[15][tid])));
      float p = __fadd_rn(__fadd_rn(__fadd_rn((float)ih, b_ih[j]), (float)hh), b_hh[j]);
      float hf = (float)tanh((double)p);
      s_h[j] = hf;
      st_pack(&h_own[tid], (uint32_t)(t + 1), __float_as_uint(hf));
      __atomic_signal_fence(__ATOMIC_SEQ_CST);
      uint32_t hb = poll_pack(&h_oth[tid], (uint32_t)(t + 1));
      s_h[(own0 ^ 256) + tid] = __uint_as_float(hb);
    }
    __syncthreads();  // (j) full h_{t+1} ready — B proceeds to next iter's P0

    // ---- P4 (A only): time/score/softmax/sample/output/broadcast
    if (isA) {
      if (tid < DD) {
        double hv = (double)s_h[tid];
        double pt = hv * (double)W_time[tid];
        double pm = hv * (double)W_mk[EE + tid];
        for (int off = 32; off > 0; off >>= 1) {
          pt += __shfl_down(pt, off);
          pm += __shfl_down(pm, off);
        }
        if ((tid & 63) == 0) { s_rt[tid >> 6] = pt; s_rm[tid >> 6] = pm; }
      } else {
        int l32 = tid & 31;
        const float4* wm4 = (const float4*)W_mk;
        float4 wm0 = wm4[2 * l32], wm1 = wm4[2 * l32 + 1];
        double acc = 0.0;
        acc = fma((double)ev0.x, (double)wm0.x, acc);
        acc = fma((double)ev0.y, (double)wm0.y, acc);
        acc = fma((double)ev0.z, (double)wm0.z, acc);
        acc = fma((double)ev0.w, (double)wm0.w, acc);
        acc = fma((double)ev1.x, (double)wm1.x, acc);
        acc = fma((double)ev1.y, (double)wm1.y, acc);
        acc = fma((double)ev1.z, (double)wm1.z, acc);
        acc = fma((double)ev1.w, (double)wm1.w, acc);
        for (int off = 16; off > 0; off >>= 1) acc += __shfl_down(acc, off, 32);
        if (l32 == 0) s_edot[(tid - 512) >> 5] = acc;
      }
      __syncthreads();  // (k)

      if (tid < KK) {
        double hmk = ((s_rm[0] + s_rm[1]) + (s_rm[2] + s_rm[3]))
                   + ((s_rm[4] + s_rm[5]) + (s_rm[6] + s_rm[7]));
        float sc = __fadd_rn((float)(s_edot[tid] + hmk), b_mk[0]);
        float mx = sc;
        for (int k = 0; k < KK; ++k) mx = fmaxf(mx, __shfl(sc, k));
        float ee = expf(__fsub_rn(sc, mx));
        float ssum = 0.0f;
        for (int k = 0; k < KK; ++k) ssum = __fadd_rn(ssum, __shfl(ee, k));
        float cp = s_prob[s_chosen];
        float at = __fmul_rn(cp, __fdiv_rn(ee, ssum));
        if (tid == 0) s_prob[s_chosen] = at;
        else          s_prob[1 + t * (KK - 1) + (tid - 1)] = at;
      } else if (tid == 16) {
        double ht = ((s_rt[0] + s_rt[1]) + (s_rt[2] + s_rt[3]))
                  + ((s_rt[4] + s_rt[5]) + (s_rt[6] + s_rt[7]));
        float td = __fadd_rn((float)ht, b_time[0]);
        float sp = __fadd_rn(fmaxf(td, 0.0f), log1pf(expf(-fabsf(td))));
        s_newt = __fadd_rn(s_last_t, sp);
      }
      __syncthreads();  // (l)

      const int active = 16 + 15 * t;
      const uint32_t kk0 = s_k0, kk1 = s_k1;
      float bz = -3.0e38f;
      int   bi = 0x7FFFFFFF;
      for (int l = tid; l < active; l += 1024) {
        uint32_t i = (uint32_t)(row * LL + l);
        uint32_t o0, o1;
        tf2x32(kk0, kk1, 0u, i, o0, o1);
        float g  = jax_gumbel(o0 ^ o1);
        float pr = s_prob[l];
        float z  = (pr > 0.0f) ? __fadd_rn(logf(fmaxf(pr, 1e-38f)), g)
                               : __fadd_rn(-1e30f, g);
        if (z > bz) { bz = z; bi = l; }
      }
      for (int off = 32; off > 0; off >>= 1) {
        float oz = __shfl_down(bz, off);
        int   oi = __shfl_down(bi, off);
        if (oz > bz || (oz == bz && oi < bi)) { bz = oz; bi = oi; }
      }
      if ((tid & 63) == 0) { s_red_z[tid >> 6] = bz; s_red_i[tid >> 6] = bi; }
      __syncthreads();  // (m)

      if (tid == 0) {
        float z0 = s_red_z[0]; int i0 = s_red_i[0];
        for (int w = 1; w < 16; ++w) {
          if (s_red_z[w] > z0 || (s_red_z[w] == z0 && s_red_i[w] < i0)) {
            z0 = s_red_z[w]; i0 = s_red_i[w];
          }
        }
        int   nm  = s_cand[i0];
        float np_ = s_nrec[i0];
        float sp_ = s_prob[i0];
        float nt  = s_newt;
        out[0 * BB * SS + row * SS + (t + 1)] = (float)nm;
        out[1 * BB * SS + row * SS + (t + 1)] = nt;
        out[2 * BB * SS + row * SS + (t + 1)] = (nt < 1000.0f) ? 1.0f : 0.0f;
        out[3 * BB * SS + row * SS + (t + 1)] = np_;
        out[4 * BB * SS + row * SS + (t + 1)] = sp_;
        s_chosen = i0; s_last_m = nm; s_last_t = nt;
        // broadcast to B: tagged words, relaxed (value travels with tag)
        st_pack(w_mark, (uint32_t)(t + 1), (uint32_t)nm);
        st_pack(w_time, (uint32_t)(t + 1), __float_as_uint(nt));
      }
      __syncthreads();  // (n)
    }
  }
}

extern "C" void kernel_launch(void* const* d_in, const int* in_sizes, int n_in,
                              void* d_out, int out_size, void* d_ws, size_t ws_size,
                              hipStream_t stream) {
  (void)in_sizes; (void)n_in; (void)out_size; (void)d_ws; (void)ws_size;
  const int*   marker_data   = (const int*)  d_in[0];
  const float* time_data     = (const float*)d_in[1];
  const float* mask_data     = (const float*)d_in[2];
  const float* embedding     = (const float*)d_in[3];
  const int*   neighbor_list = (const int*)  d_in[4];
  const float* neighbor_prob = (const float*)d_in[5];
  const float* W_te   = (const float*)d_in[6];
  const float* b_te   = (const float*)d_in[7];
  const float* W_el   = (const float*)d_in[8];
  const float* b_el   = (const float*)d_in[9];
  const float* W_ih   = (const float*)d_in[10];
  const float* b_ih   = (const float*)d_in[11];
  const float* W_hh   = (const float*)d_in[12];
  const float* b_hh   = (const float*)d_in[13];
  const float* W_time = (const float*)d_in[14];
  const float* b_time = (const float*)d_in[15];
  const float* W_mk   = (const float*)d_in[16];
  const float* b_mk   = (const float*)d_in[17];
  float* out = (float*)d_out;

  // zero comm tags every launch (graph-replay safe; ~10 us)
  int total = (int)(((size_t)BB * ROW_U64 + 1023) / 1024);
  hipLaunchKernelGGL(init_comm_kernel, dim3(total), dim3(1024), 0, stream);
  hipLaunchKernelGGL(rnn_pair_kernel, dim3(2 * BB), dim3(1024), 0, stream,
                     marker_data, time_data, mask_data, embedding,
                     neighbor_list, neighbor_prob,
                     W_te, b_te, W_el, b_el, W_ih, b_ih, W_hh, b_hh,
                     W_time, b_time, W_mk, b_mk, out);
}